// Round 6
// baseline (1811.043 us; speedup 1.0000x reference)
//
#include <hip/hip_runtime.h>

#define N_NODES 50000
#define C_FEAT  64
#define E_EDGES 800000
#define KEYS    400000              // dst*8 + t
#define NCHUNK  196                 // ceil(KEYS/2048); chunk = 512 thr x int4
#define DPB     16                  // dsts per conv tile -> 16 MFMA rows
#define NTILES  (N_NODES / DPB)     // 3125
#define DPART   6250                // dsts per XCD partition (scatter)
#define GRID    1024                // 4 blocks/CU x 256 CU (co-resident)
#define NTHR    512
#define GTH     (GRID * NTHR)       // 524288 threads
#define HIST_BASE 324288            // GTH - 200000 hist jobs (4 edges each)
#define SCAT_JOBS 3128              // 391 tiles x 8 XCD groups (2048 edges/tile)
#define ADV_JOBS  782               // 64-node tiles

typedef __attribute__((ext_vector_type(8))) short short8;
typedef __attribute__((ext_vector_type(4))) float f32x4;

__device__ __forceinline__ float bf2f(unsigned short u) {
    union { unsigned int i; float f; } v; v.i = ((unsigned int)u) << 16; return v.f;
}
__device__ __forceinline__ unsigned short f2bf(float f) {
    union { float f; unsigned int i; } v; v.f = f;
    unsigned int r = v.i + 0x7fff + ((v.i >> 16) & 1);   // RNE
    return (unsigned short)(r >> 16);
}

// Software grid barrier. Grid == exactly co-resident capacity (see launch
// bounds math in header comment). Release: syncthreads drains each wave's
// stores to L2 (compiler emits s_waitcnt vmcnt(0) before s_barrier), thread0's
// threadfence writes back the XCD L2 (agent-scope release). Acquire: spin on
// agent atomic, then all threads fence (invalidate L1/L2) before reads.
__device__ __forceinline__ void grid_bar(int* bar, int target) {
    __syncthreads();
    if (threadIdx.x == 0) {
        __threadfence();
        __hip_atomic_fetch_add(bar, 1, __ATOMIC_ACQ_REL, __HIP_MEMORY_SCOPE_AGENT);
        while (__hip_atomic_load(bar, __ATOMIC_ACQUIRE, __HIP_MEMORY_SCOPE_AGENT) < target)
            __builtin_amdgcn_s_sleep(2);
    }
    __syncthreads();
    __threadfence();
}

// -------- conv phase: 8 waves x 2 dsts, 16-deep gather pipeline, MFMA --------
// (proven 47.2us structure from R2/R5, chunk shift 10 -> 11)
#define FLUSH(T, V)                                                                   \
    { int _t = (T);                                                                   \
      if (_t != cur) { scat[dl][cur * 64 + c] = f2bf(acc); acc = 0.f; cur = _t; }     \
      acc += (V); }

#define EDGE(K)                                                                       \
    int p##K = __builtin_amdgcn_readlane(pv, e + K);                                  \
    float v##K = bf2f(Xb[(size_t)(p##K & 0xffff) * 64 + c]);

__device__ __forceinline__ void conv_phase(unsigned short (*scat)[520],
                                           const unsigned short* __restrict__ Xb,
                                           const unsigned short* __restrict__ WT,
                                           const float* __restrict__ bias,
                                           const int* __restrict__ segend,
                                           const int* __restrict__ chunkoff,
                                           const int* __restrict__ elist,
                                           unsigned short* __restrict__ Hb,
                                           int lane, int wave, int bid) {
    const int c = lane;
    for (int tile = bid; tile < NTILES; tile += GRID) {
        const int dbase = tile * DPB;
        {   // zero own 2 rows
            short8 z = {};
            *(short8*)&scat[wave * 2 + 0][lane * 8] = z;
            *(short8*)&scat[wave * 2 + 1][lane * 8] = z;
        }
        int sbeg[2], send_[2], pvw[2];
        #pragma unroll
        for (int q = 0; q < 2; ++q) {
            const int d = dbase + wave * 2 + q;
            const int k0 = d * 8;
            sbeg[q]  = (d == 0) ? 0 : chunkoff[(k0 - 1) >> 11] + segend[k0 - 1];
            send_[q] = chunkoff[(k0 + 7) >> 11] + segend[k0 + 7];
        }
        #pragma unroll
        for (int q = 0; q < 2; ++q)
            pvw[q] = (lane < send_[q] - sbeg[q]) ? elist[sbeg[q] + lane] : 0;

        #pragma unroll
        for (int q = 0; q < 2; ++q) {
            const int dl = wave * 2 + q;
            int i = sbeg[q];
            const int end = send_[q];
            int pv = pvw[q];
            int cur = 0;
            float acc = 0.f;
            while (i < end) {
                int cnt = end - i; cnt = (cnt > 64) ? 64 : cnt;
                int pvn = 0;
                if (i + 64 < end) pvn = (lane < end - i - 64) ? elist[i + 64 + lane] : 0;
                int e = 0;
                for (; e + 15 < cnt; e += 16) {           // 16 gathers in flight
                    EDGE(0)  EDGE(1)  EDGE(2)  EDGE(3)
                    EDGE(4)  EDGE(5)  EDGE(6)  EDGE(7)
                    EDGE(8)  EDGE(9)  EDGE(10) EDGE(11)
                    EDGE(12) EDGE(13) EDGE(14) EDGE(15)
                    FLUSH(p0 >> 16, v0)   FLUSH(p1 >> 16, v1)
                    FLUSH(p2 >> 16, v2)   FLUSH(p3 >> 16, v3)
                    FLUSH(p4 >> 16, v4)   FLUSH(p5 >> 16, v5)
                    FLUSH(p6 >> 16, v6)   FLUSH(p7 >> 16, v7)
                    FLUSH(p8 >> 16, v8)   FLUSH(p9 >> 16, v9)
                    FLUSH(p10 >> 16, v10) FLUSH(p11 >> 16, v11)
                    FLUSH(p12 >> 16, v12) FLUSH(p13 >> 16, v13)
                    FLUSH(p14 >> 16, v14) FLUSH(p15 >> 16, v15)
                }
                if (e + 7 < cnt) {
                    EDGE(0) EDGE(1) EDGE(2) EDGE(3) EDGE(4) EDGE(5) EDGE(6) EDGE(7)
                    FLUSH(p0 >> 16, v0) FLUSH(p1 >> 16, v1)
                    FLUSH(p2 >> 16, v2) FLUSH(p3 >> 16, v3)
                    FLUSH(p4 >> 16, v4) FLUSH(p5 >> 16, v5)
                    FLUSH(p6 >> 16, v6) FLUSH(p7 >> 16, v7)
                    e += 8;
                }
                if (e + 3 < cnt) {
                    EDGE(0) EDGE(1) EDGE(2) EDGE(3)
                    FLUSH(p0 >> 16, v0) FLUSH(p1 >> 16, v1)
                    FLUSH(p2 >> 16, v2) FLUSH(p3 >> 16, v3)
                    e += 4;
                }
                if (e + 1 < cnt) {
                    EDGE(0) EDGE(1)
                    FLUSH(p0 >> 16, v0) FLUSH(p1 >> 16, v1)
                    e += 2;
                }
                if (e < cnt) {
                    EDGE(0)
                    FLUSH(p0 >> 16, v0)
                }
                i += 64;
                pv = pvn;
            }
            scat[dl][cur * 64 + c] = f2bf(acc);
        }
        __syncthreads();

        // MFMA [16,512]@[512,64] on waves 0..3; C/D col=lane&15, row=quad*4+r
        if (wave < 4) {
            const int m = lane & 15;
            const int quad = lane >> 4;
            const int n0 = wave * 16;
            f32x4 acc4 = {0.f, 0.f, 0.f, 0.f};
            const unsigned short* wrow = WT + (size_t)(n0 + m) * 512;
            #pragma unroll
            for (int kc = 0; kc < 16; ++kc) {
                short8 af = *(const short8*)&scat[m][kc * 32 + quad * 8];
                short8 bf = *(const short8*)(wrow + kc * 32 + quad * 8);
                acc4 = __builtin_amdgcn_mfma_f32_16x16x32_bf16(af, bf, acc4, 0, 0, 0);
            }
            const int col = n0 + m;
            const float bcol = bias[col];
            #pragma unroll
            for (int r = 0; r < 4; ++r) {
                int node = dbase + quad * 4 + r;
                Hb[(size_t)node * 64 + col] = f2bf(fmaxf(acc4[r] + bcol, 0.f));
            }
        }
        __syncthreads();   // MFMA readers done before next tile's zeroing
    }
}

// -------- mega kernel: all 7 pipeline stages, 6 grid barriers, 1 dispatch --------
__global__ __launch_bounds__(512, 8) void fused_all(
    const float* __restrict__ x,
    const int* __restrict__ src, const int* __restrict__ dst, const int* __restrict__ tixp,
    const float* __restrict__ W1, const float* __restrict__ bt1,
    const float* __restrict__ W2, const float* __restrict__ bt2,
    const float* __restrict__ Wa1, const float* __restrict__ ba1,
    const float* __restrict__ Wa2, const float* __restrict__ ba2,
    unsigned short* __restrict__ xb, unsigned short* __restrict__ h1b,
    unsigned short* __restrict__ h2b,
    unsigned short* __restrict__ WT1, unsigned short* __restrict__ WT2,
    unsigned short* __restrict__ Wa1T, unsigned short* __restrict__ Wa2T,
    int* __restrict__ cnt, int* __restrict__ bsum, int* __restrict__ chunkoff,
    int* __restrict__ bar, int* __restrict__ elist,
    float* __restrict__ out) {

    const int tid  = threadIdx.x;
    const int bid  = blockIdx.x;
    const int lane = tid & 63;
    const int wave = tid >> 6;
    const int gid  = bid * NTHR + tid;

    // LDS pool: conv scat 16x520x2=16640B; adv sH 64x72x2=9216B + sT 64x136x2=17408B
    __shared__ __attribute__((aligned(16))) unsigned char pool[26624];
    unsigned short (*scat)[520] = (unsigned short(*)[520])pool;
    unsigned short (*sH)[72]    = (unsigned short(*)[72])pool;
    unsigned short (*sT)[136]   = (unsigned short(*)[136])(pool + 9216);
    __shared__ int wsum[8];

    // ---- P0: x->bf16 + W/Wa transposes + single-pass hist (cnt zeroed by memset) ----
    if (gid < 400000) {                       // x convert: 8 elems/thread, exact
        int base = gid * 8;
        float4 a = *(const float4*)(x + base);
        float4 c4 = *(const float4*)(x + base + 4);
        short8 o;
        o[0] = (short)f2bf(a.x); o[1] = (short)f2bf(a.y);
        o[2] = (short)f2bf(a.z); o[3] = (short)f2bf(a.w);
        o[4] = (short)f2bf(c4.x); o[5] = (short)f2bf(c4.y);
        o[6] = (short)f2bf(c4.z); o[7] = (short)f2bf(c4.w);
        *(short8*)(xb + base) = o;
    } else if (gid < 432768) {                // WT1/WT2 [64][512] <- W[512][64]
        int i = gid - 400000;
        int n = i >> 9, k = i & 511;
        WT1[i] = f2bf(W1[k * 64 + n]);
        WT2[i] = f2bf(W2[k * 64 + n]);
    } else if (gid < 449152) {                // Wa transposes
        int i = gid - 432768;
        if (i < 8192) { int n = i >> 6, k = i & 63;  Wa1T[i] = f2bf(Wa1[k * 128 + n]); }
        else { int ii = i - 8192; int n = ii >> 7, k = ii & 127; Wa2T[ii] = f2bf(Wa2[k * 64 + n]); }
    }
    if (gid >= HIST_BASE) {                   // hist: 4 edges/thread, fire-and-forget
        int e0 = (gid - HIST_BASE) * 4;
        int4 d = *(const int4*)(dst + e0);
        int4 t = *(const int4*)(tixp + e0);
        atomicAdd(&cnt[d.x * 8 + t.x], 1);
        atomicAdd(&cnt[d.y * 8 + t.y], 1);
        atomicAdd(&cnt[d.z * 8 + t.z], 1);
        atomicAdd(&cnt[d.w * 8 + t.w], 1);
    }
    grid_bar(bar, 1 * GRID);

    // ---- P1: per-chunk exclusive scan (2048 ints/chunk, blocks 0..195) ----
    if (bid < NCHUNK) {
        const int i4 = bid * NTHR + tid;
        int4 v = make_int4(0, 0, 0, 0);
        const bool ok = (i4 * 4 < KEYS);
        if (ok) v = ((const int4*)cnt)[i4];
        int s = v.x + v.y + v.z + v.w;
        int sc = s;
        #pragma unroll
        for (int d = 1; d < 64; d <<= 1) {
            int o = __shfl_up(sc, d, 64);
            if (lane >= d) sc += o;
        }
        if (lane == 63) wsum[wave] = sc;
        __syncthreads();
        int wbase = 0;
        #pragma unroll
        for (int w = 0; w < 8; ++w) wbase += (w < wave) ? wsum[w] : 0;
        int base = wbase + sc - s;
        int4 o4;
        o4.x = base; o4.y = base + v.x; o4.z = o4.y + v.y; o4.w = o4.z + v.z;
        if (ok) ((int4*)cnt)[i4] = o4;
        if (tid == NTHR - 1) bsum[bid] = wbase + sc;
    }
    grid_bar(bar, 2 * GRID);

    // ---- P2: block 0 scans 196 chunk totals -> chunkoff ----
    if (bid == 0 && wave == 0) {
        int carry = 0;
        #pragma unroll
        for (int g2 = 0; g2 < (NCHUNK + 63) / 64; ++g2) {
            int j = g2 * 64 + lane;
            int val = (j < NCHUNK) ? bsum[j] : 0;
            int scn = val;
            #pragma unroll
            for (int d = 1; d < 64; d <<= 1) {
                int o = __shfl_up(scn, d, 64);
                if (lane >= d) scn += o;
            }
            if (j < NCHUNK) chunkoff[j] = carry + scn - val;
            carry += __shfl(scn, 63, 64);
        }
    }
    grid_bar(bar, 3 * GRID);

    // ---- P3: scatter, 8-pass XCD-partitioned (R4 lesson: keeps elist writers
    // XCD-local, 6MB not 55MB write traffic), 4 edges/thread ----
    for (int job = bid; job < SCAT_JOBS; job += GRID) {   // GRID%8==0 -> g fixed/block
        const int g = job & 7;
        const int tile = job >> 3;
        const int lo = g * DPART;
        const int e0 = tile * 2048 + tid * 4;
        if (e0 < E_EDGES) {
            int4 d = *(const int4*)(dst + e0);
            int4 t = *(const int4*)(tixp + e0);
            int4 s = *(const int4*)(src + e0);
            int dd[4] = {d.x, d.y, d.z, d.w};
            int tt[4] = {t.x, t.y, t.z, t.w};
            int ss[4] = {s.x, s.y, s.z, s.w};
            #pragma unroll
            for (int k = 0; k < 4; ++k) {
                if ((unsigned)(dd[k] - lo) < (unsigned)DPART) {
                    int key = dd[k] * 8 + tt[k];
                    int pos = chunkoff[key >> 11] + atomicAdd(&cnt[key], 1);
                    elist[pos] = ss[k] | (tt[k] << 16);
                }
            }
        }
    }
    grid_bar(bar, 4 * GRID);

    // ---- P4: conv1 (x -> h1) ----
    conv_phase(scat, xb, WT1, bt1, cnt, chunkoff, elist, h1b, lane, wave, bid);
    grid_bar(bar, 5 * GRID);

    // ---- P5: conv2 (h1 -> h2) ----
    conv_phase(scat, h1b, WT2, bt2, cnt, chunkoff, elist, h2b, lane, wave, bid);
    grid_bar(bar, 6 * GRID);

    // ---- P6: adversary MLP + h1 residual; 8 waves: rows by wave&3, cols by wave>>2 ----
    for (int job = bid; job < ADV_JOBS; job += GRID) {
        const int nbase = job * 64;
        const int m = lane & 15;
        const int quad = lane >> 4;
        const int w4 = wave & 3;
        const int half = wave >> 2;
        const int r0 = w4 * 16;

        {   // load 64 rows of h2b into sH: 512 threads x 1 short8
            int row = tid >> 3;
            int c8 = (tid & 7) * 8;
            int node = nbase + row;
            short8 u = {};
            if (node < N_NODES)
                u = *(const short8*)(h2b + (size_t)node * C_FEAT + c8);
            *(short8*)&sH[row][c8] = u;
        }
        __syncthreads();

        {   // GEMM1: [16,64]@[64,128]; wave-half covers 4 of 8 col-tiles
            f32x4 acc1[4];
            #pragma unroll
            for (int ct = 0; ct < 4; ++ct) acc1[ct] = (f32x4){0.f, 0.f, 0.f, 0.f};
            #pragma unroll
            for (int kc = 0; kc < 2; ++kc) {
                short8 af = *(const short8*)&sH[r0 + m][kc * 32 + quad * 8];
                #pragma unroll
                for (int ct = 0; ct < 4; ++ct) {
                    int c16 = half * 4 + ct;
                    short8 bf = *(const short8*)(Wa1T + (size_t)(c16 * 16 + m) * 64 + kc * 32 + quad * 8);
                    acc1[ct] = __builtin_amdgcn_mfma_f32_16x16x32_bf16(af, bf, acc1[ct], 0, 0, 0);
                }
            }
            #pragma unroll
            for (int ct = 0; ct < 4; ++ct) {
                const int col = (half * 4 + ct) * 16 + m;
                const float b1 = ba1[col];
                #pragma unroll
                for (int r = 0; r < 4; ++r)
                    sT[r0 + quad * 4 + r][col] = f2bf(fmaxf(acc1[ct][r] + b1, 0.f));
            }
        }
        __syncthreads();

        {   // GEMM2: [16,128]@[128,64]; wave-half covers 2 of 4 col-tiles; +ba2 +h1
            f32x4 acc2[2];
            #pragma unroll
            for (int ct = 0; ct < 2; ++ct) acc2[ct] = (f32x4){0.f, 0.f, 0.f, 0.f};
            #pragma unroll
            for (int kc = 0; kc < 4; ++kc) {
                short8 af = *(const short8*)&sT[r0 + m][kc * 32 + quad * 8];
                #pragma unroll
                for (int ct = 0; ct < 2; ++ct) {
                    int c16 = half * 2 + ct;
                    short8 bf = *(const short8*)(Wa2T + (size_t)(c16 * 16 + m) * 128 + kc * 32 + quad * 8);
                    acc2[ct] = __builtin_amdgcn_mfma_f32_16x16x32_bf16(af, bf, acc2[ct], 0, 0, 0);
                }
            }
            #pragma unroll
            for (int ct = 0; ct < 2; ++ct) {
                const int col = (half * 2 + ct) * 16 + m;
                const float b2 = ba2[col];
                #pragma unroll
                for (int r = 0; r < 4; ++r) {
                    int node = nbase + r0 + quad * 4 + r;
                    if (node < N_NODES) {
                        float val = acc2[ct][r] + b2 + bf2f(h1b[(size_t)node * 64 + col]);
                        out[(size_t)node * 64 + col] = val;
                    }
                }
            }
        }
        __syncthreads();
    }
}

extern "C" void kernel_launch(void* const* d_in, const int* in_sizes, int n_in,
                              void* d_out, int out_size, void* d_ws, size_t ws_size,
                              hipStream_t stream) {
    const float* x   = (const float*)d_in[0];
    const int*   ei  = (const int*)d_in[1];
    const int*   tix = (const int*)d_in[2];
    const float* Wt1 = (const float*)d_in[3];
    const float* bt1 = (const float*)d_in[4];
    const float* Wt2 = (const float*)d_in[5];
    const float* bt2 = (const float*)d_in[6];
    const float* Wa1 = (const float*)d_in[7];
    const float* ba1 = (const float*)d_in[8];
    const float* Wa2 = (const float*)d_in[9];
    const float* ba2 = (const float*)d_in[10];
    float* out = (float*)d_out;

    const int* src = ei;
    const int* dst = ei + E_EDGES;

    // workspace (~25 MB)
    unsigned short* xb   = (unsigned short*)d_ws;          // [N,64] bf16
    unsigned short* h1b  = xb + (size_t)N_NODES * 64;      // [N,64] bf16
    unsigned short* h2b  = h1b + (size_t)N_NODES * 64;     // [N,64] bf16
    unsigned short* WT1  = h2b + (size_t)N_NODES * 64;     // [64,512] bf16
    unsigned short* WT2  = WT1 + 64 * 512;
    unsigned short* Wa1T = WT2 + 64 * 512;                 // [128,64] bf16
    unsigned short* Wa2T = Wa1T + 8192;                    // [64,128] bf16
    int* cnt      = (int*)(Wa2T + 8192);                   // KEYS
    int* bsum     = cnt + KEYS;                            // 512
    int* chunkoff = bsum + 512;                            // 512
    int* bar      = chunkoff + 512;                        // 64 (1 used: grid barrier)
    int* elist    = bar + 64;                              // E packed (src | t<<16)

    hipMemsetAsync(cnt, 0, (KEYS + 512 + 512 + 64) * sizeof(int), stream);
    fused_all<<<GRID, NTHR, 0, stream>>>(
        x, src, dst, tix, Wt1, bt1, Wt2, bt2, Wa1, ba1, Wa2, ba2,
        xb, h1b, h2b, WT1, WT2, Wa1T, Wa2T,
        cnt, bsum, chunkoff, bar, elist, out);
}

// Round 7
// 296.931 us; speedup vs baseline: 6.0992x; 6.0992x over previous
//
#include <hip/hip_runtime.h>

#define N_NODES 50000
#define C_FEAT  64
#define E_EDGES 800000
#define KEYS    400000          // dst*8 + t
#define NBLK1   391             // ceil(KEYS/1024)
#define DPB     16              // dsts per conv tile -> 16 MFMA rows
#define NTILES  (N_NODES / DPB) // 3125
#define PBLK_X  1563            // x->bf16 cvt blocks (8 elems/thread, last partial)
#define PBLK_W  128             // Wt transpose blocks
#define PBLK_A  64              // Wa1T/Wa2T transpose blocks (2 x 8192)
#define PBLK_P  391             // partition+hist blocks (2048 edges each)
#define DPART   6250            // dsts per XCD partition
#define BUCKSZ  131072          // staging records per XCD bucket (mean 100k, sigma~300)
#define CONV_GRID 1024          // persistent: 4 blocks/CU x 256 CU

typedef __attribute__((ext_vector_type(8))) short short8;
typedef __attribute__((ext_vector_type(4))) float f32x4;

__device__ __forceinline__ float bf2f(unsigned short u) {
    union { unsigned int i; float f; } v; v.i = ((unsigned int)u) << 16; return v.f;
}
__device__ __forceinline__ unsigned short f2bf(float f) {
    union { float f; unsigned int i; } v; v.f = f;
    unsigned int r = v.i + 0x7fff + ((v.i >> 16) & 1);   // RNE
    return (unsigned short)(r >> 16);
}

// -------- prep (x->bf16, W transposes) + fused hist + LDS radix partition --------
// Partition blocks read each edge ONCE, count into cnt (hist) AND bucket compact
// records (src|t<<16, key) by XCD partition g=dst/DPART. Chunks are reserved with
// one atomicAdd per bucket so each staging line is written by one block (R4
// lesson: cross-XCD partial-line writes blew writes up 8x).
__global__ __launch_bounds__(256) void prep_hist(const float* __restrict__ x,
                                                 const float* __restrict__ W1,
                                                 const float* __restrict__ W2,
                                                 const float* __restrict__ Wa1,
                                                 const float* __restrict__ Wa2,
                                                 const int* __restrict__ src,
                                                 const int* __restrict__ dst,
                                                 const int* __restrict__ tix,
                                                 unsigned short* __restrict__ xb,
                                                 unsigned short* __restrict__ WT1,
                                                 unsigned short* __restrict__ WT2,
                                                 unsigned short* __restrict__ Wa1T,
                                                 unsigned short* __restrict__ Wa2T,
                                                 int* __restrict__ cnt,
                                                 int* __restrict__ bcur,
                                                 int2* __restrict__ staging) {
    __shared__ int lcnt[8], lbase[8], lcur[8], gbase[8];
    __shared__ int2 lrec[2048];
    const int b = blockIdx.x;
    if (b < PBLK_X) {
        int base = (b * 256 + threadIdx.x) * 8;
        if (base < N_NODES * 64) {
            float4 a = *(const float4*)(x + base);
            float4 c = *(const float4*)(x + base + 4);
            short8 o;
            o[0] = (short)f2bf(a.x); o[1] = (short)f2bf(a.y);
            o[2] = (short)f2bf(a.z); o[3] = (short)f2bf(a.w);
            o[4] = (short)f2bf(c.x); o[5] = (short)f2bf(c.y);
            o[6] = (short)f2bf(c.z); o[7] = (short)f2bf(c.w);
            *(short8*)(xb + base) = o;
        }
    } else if (b < PBLK_X + PBLK_W) {
        int i = (b - PBLK_X) * 256 + threadIdx.x;      // 32768
        int n = i >> 9, k = i & 511;
        WT1[i] = f2bf(W1[k * 64 + n]);
        WT2[i] = f2bf(W2[k * 64 + n]);
    } else if (b < PBLK_X + PBLK_W + PBLK_A) {
        int i = (b - PBLK_X - PBLK_W) * 256 + threadIdx.x;   // 0..16383
        if (i < 8192) {                                // Wa1T[128][64] <- Wa1[64][128]
            int n = i >> 6, k = i & 63;
            Wa1T[i] = f2bf(Wa1[k * 128 + n]);
        } else {                                       // Wa2T[64][128] <- Wa2[128][64]
            int ii = i - 8192;
            int n = ii >> 7, k = ii & 127;
            Wa2T[ii] = f2bf(Wa2[k * 64 + n]);
        }
    } else {
        // ---- partition + hist: 2048 edges/block, read once ----
        int bb = b - PBLK_X - PBLK_W - PBLK_A;         // 0..390
        const int e0 = bb * 2048 + threadIdx.x * 8;
        const bool valid = (e0 < E_EDGES);             // E%8==0 -> group fully in-bounds
        if (threadIdx.x < 8) { lcnt[threadIdx.x] = 0; lcur[threadIdx.x] = 0; }
        int dd[8], tt[8], ss[8];
        if (valid) {
            int4 d0 = *(const int4*)(dst + e0);
            int4 d1 = *(const int4*)(dst + e0 + 4);
            int4 t0 = *(const int4*)(tix + e0);
            int4 t1 = *(const int4*)(tix + e0 + 4);
            int4 s0 = *(const int4*)(src + e0);
            int4 s1 = *(const int4*)(src + e0 + 4);
            dd[0]=d0.x; dd[1]=d0.y; dd[2]=d0.z; dd[3]=d0.w;
            dd[4]=d1.x; dd[5]=d1.y; dd[6]=d1.z; dd[7]=d1.w;
            tt[0]=t0.x; tt[1]=t0.y; tt[2]=t0.z; tt[3]=t0.w;
            tt[4]=t1.x; tt[5]=t1.y; tt[6]=t1.z; tt[7]=t1.w;
            ss[0]=s0.x; ss[1]=s0.y; ss[2]=s0.z; ss[3]=s0.w;
            ss[4]=s1.x; ss[5]=s1.y; ss[6]=s1.z; ss[7]=s1.w;
        }
        __syncthreads();
        if (valid) {
            #pragma unroll
            for (int k = 0; k < 8; ++k) {
                atomicAdd(&cnt[dd[k] * 8 + tt[k]], 1);       // hist (global offsets later)
                atomicAdd(&lcnt[dd[k] / DPART], 1);          // bucket count
            }
        }
        __syncthreads();
        if (threadIdx.x == 0) {
            int run = 0;
            #pragma unroll
            for (int g = 0; g < 8; ++g) { lbase[g] = run; run += lcnt[g]; }
        }
        __syncthreads();
        if (valid) {
            #pragma unroll
            for (int k = 0; k < 8; ++k) {
                int g = dd[k] / DPART;
                int p = lbase[g] + atomicAdd(&lcur[g], 1);
                lrec[p] = make_int2(ss[k] | (tt[k] << 16), dd[k] * 8 + tt[k]);
            }
        }
        __syncthreads();
        if (threadIdx.x < 8)
            gbase[threadIdx.x] = atomicAdd(&bcur[threadIdx.x], lcnt[threadIdx.x]);
        __syncthreads();
        #pragma unroll
        for (int g = 0; g < 8; ++g) {
            const int n = lcnt[g], lb = lbase[g], gb = gbase[g];
            for (int i = threadIdx.x; i < n; i += 256)
                staging[(size_t)g * BUCKSZ + gb + i] = lrec[lb + i];
        }
    }
}

// -------- scan_all: per-chunk local scan; LAST block scans chunk totals --------
__global__ __launch_bounds__(256) void scan_all(int* __restrict__ cnt,
                                                int* __restrict__ bsum,
                                                int* __restrict__ chunkoff,
                                                int* __restrict__ done) {
    __shared__ int wsum[4];
    __shared__ int ticket;
    const int tid = threadIdx.x;
    const int lane = tid & 63;
    const int wave = tid >> 6;
    const int i4 = blockIdx.x * 256 + tid;
    int4 v = make_int4(0, 0, 0, 0);
    const bool ok = (i4 * 4 < KEYS);
    if (ok) v = ((const int4*)cnt)[i4];
    int s = v.x + v.y + v.z + v.w;
    int sc = s;
    #pragma unroll
    for (int d = 1; d < 64; d <<= 1) {
        int o = __shfl_up(sc, d, 64);
        if (lane >= d) sc += o;
    }
    if (lane == 63) wsum[wave] = sc;
    __syncthreads();
    int wbase = 0;
    #pragma unroll
    for (int w = 0; w < 4; ++w) wbase += (w < wave) ? wsum[w] : 0;
    int base = wbase + sc - s;
    int4 o;
    o.x = base;
    o.y = base + v.x;
    o.z = o.y + v.y;
    o.w = o.z + v.z;
    if (ok) ((int4*)cnt)[i4] = o;
    if (tid == 255) {
        bsum[blockIdx.x] = wbase + sc;
        __threadfence();
        ticket = atomicAdd(done, 1);
    }
    __syncthreads();
    if (ticket == NBLK1 - 1 && wave == 0) {
        int carry = 0;
        #pragma unroll
        for (int g = 0; g < (NBLK1 + 63) / 64; ++g) {
            int j = g * 64 + lane;
            int val = (j < NBLK1) ? atomicAdd(&bsum[j], 0) : 0;
            int scn = val;
            #pragma unroll
            for (int d = 1; d < 64; d <<= 1) {
                int oo = __shfl_up(scn, d, 64);
                if (lane >= d) scn += oo;
            }
            if (j < NBLK1) chunkoff[j] = carry + scn - val;
            carry += __shfl(scn, 63, 64);
        }
    }
}

// -------- scatter from compact staged records: group g = blockIdx&7 (XCD-affine) --------
// Reads 6.4MB total (vs 77MB for the 8-pass rescan); elist/cnt writers XCD-local.
__global__ __launch_bounds__(256) void scatter_edges(const int2* __restrict__ staging,
                                                     const int* __restrict__ bcur,
                                                     int* __restrict__ cursor,
                                                     const int* __restrict__ chunkoff,
                                                     int* __restrict__ elist) {
    const int g = blockIdx.x & 7;
    const int j = blockIdx.x >> 3;                   // 0..127 (128*1024 = BUCKSZ)
    const int nrec = bcur[g];
    const int r0 = j * 1024 + threadIdx.x * 4;
    if (r0 >= nrec) return;
    const int2* base = staging + (size_t)g * BUCKSZ;
    int4 a = *(const int4*)(base + r0);              // recs r0, r0+1
    int4 b = *(const int4*)(base + r0 + 2);          // recs r0+2, r0+3
    {
        int pos = chunkoff[a.y >> 10] + atomicAdd(&cursor[a.y], 1);
        elist[pos] = a.x;
    }
    if (r0 + 1 < nrec) {
        int pos = chunkoff[a.w >> 10] + atomicAdd(&cursor[a.w], 1);
        elist[pos] = a.z;
    }
    if (r0 + 2 < nrec) {
        int pos = chunkoff[b.y >> 10] + atomicAdd(&cursor[b.y], 1);
        elist[pos] = b.x;
    }
    if (r0 + 3 < nrec) {
        int pos = chunkoff[b.w >> 10] + atomicAdd(&cursor[b.w], 1);
        elist[pos] = b.z;
    }
}

// -------- fused conv: persistent, 8 waves, dynamic dst queue (depth-2), MFMA --------
#define FLUSH(T, V)                                                                   \
    { int _t = (T);                                                                   \
      if (_t != cur) { scat[dl][cur * 64 + c] = f2bf(acc); acc = 0.f; cur = _t; }     \
      acc += (V); }

#define EDGE(K)                                                                       \
    int p##K = __builtin_amdgcn_readlane(pv, e + K);                                  \
    float v##K = bf2f(Xb[(size_t)(p##K & 0xffff) * 64 + c]);

__global__ __launch_bounds__(512, 8) void fused_conv(const unsigned short* __restrict__ Xb,
                                                     const unsigned short* __restrict__ WT,
                                                     const float* __restrict__ bias,
                                                     const int* __restrict__ segend,   // local ends
                                                     const int* __restrict__ chunkoff,
                                                     const int* __restrict__ elist,
                                                     unsigned short* __restrict__ Hb) {
    __shared__ unsigned short scat[DPB][520];
    __shared__ int nextd;
    const int lane = threadIdx.x & 63;
    const int wave = threadIdx.x >> 6;               // 0..7
    const int c = lane;

    for (int tile = blockIdx.x; tile < NTILES; tile += CONV_GRID) {
        const int dbase = tile * DPB;

        {   // zero own 2 rows (prev tile's MFMA readers passed the tail barrier)
            short8 z = {};
            *(short8*)&scat[wave * 2 + 0][lane * 8] = z;
            *(short8*)&scat[wave * 2 + 1][lane * 8] = z;
        }
        if (threadIdx.x == 0) nextd = 0;
        __syncthreads();

        // dynamic dst queue, depth-2 pipelined: grab+prefetch next while
        // processing current (keeps R2's descriptor/pv prefetch overlap AND
        // balances segment-length variance across waves)
        int q_ = 0;
        if (lane == 0) q_ = atomicAdd(&nextd, 1);
        int qn = __shfl(q_, 0, 64);
        int sbn = 0, sen = 0, pvn = 0;
        if (qn < DPB) {
            const int d = dbase + qn, k0 = d * 8;
            sbn = (d == 0) ? 0 : chunkoff[(k0 - 1) >> 10] + segend[k0 - 1];
            sen = chunkoff[(k0 + 7) >> 10] + segend[k0 + 7];
            pvn = (lane < sen - sbn) ? elist[sbn + lane] : 0;
        }
        while (qn < DPB) {
            const int dl = qn;
            int i = sbn;
            const int end = sen;
            int pv = pvn;
            // grab + prefetch next dst (loads overlap the processing below)
            int t_ = 0;
            if (lane == 0) t_ = atomicAdd(&nextd, 1);
            qn = __shfl(t_, 0, 64);
            if (qn < DPB) {
                const int d = dbase + qn, k0 = d * 8;
                sbn = (d == 0) ? 0 : chunkoff[(k0 - 1) >> 10] + segend[k0 - 1];
                sen = chunkoff[(k0 + 7) >> 10] + segend[k0 + 7];
                pvn = (lane < sen - sbn) ? elist[sbn + lane] : 0;
            }
            int cur = 0;
            float acc = 0.f;
            while (i < end) {
                int cnt = end - i; cnt = (cnt > 64) ? 64 : cnt;
                int pv2 = 0;
                if (i + 64 < end) pv2 = (lane < end - i - 64) ? elist[i + 64 + lane] : 0;
                int e = 0;
                for (; e + 15 < cnt; e += 16) {           // 16 gathers in flight
                    EDGE(0)  EDGE(1)  EDGE(2)  EDGE(3)
                    EDGE(4)  EDGE(5)  EDGE(6)  EDGE(7)
                    EDGE(8)  EDGE(9)  EDGE(10) EDGE(11)
                    EDGE(12) EDGE(13) EDGE(14) EDGE(15)
                    FLUSH(p0 >> 16, v0)   FLUSH(p1 >> 16, v1)
                    FLUSH(p2 >> 16, v2)   FLUSH(p3 >> 16, v3)
                    FLUSH(p4 >> 16, v4)   FLUSH(p5 >> 16, v5)
                    FLUSH(p6 >> 16, v6)   FLUSH(p7 >> 16, v7)
                    FLUSH(p8 >> 16, v8)   FLUSH(p9 >> 16, v9)
                    FLUSH(p10 >> 16, v10) FLUSH(p11 >> 16, v11)
                    FLUSH(p12 >> 16, v12) FLUSH(p13 >> 16, v13)
                    FLUSH(p14 >> 16, v14) FLUSH(p15 >> 16, v15)
                }
                if (e + 7 < cnt) {                        // tail tier 8
                    EDGE(0) EDGE(1) EDGE(2) EDGE(3) EDGE(4) EDGE(5) EDGE(6) EDGE(7)
                    FLUSH(p0 >> 16, v0) FLUSH(p1 >> 16, v1)
                    FLUSH(p2 >> 16, v2) FLUSH(p3 >> 16, v3)
                    FLUSH(p4 >> 16, v4) FLUSH(p5 >> 16, v5)
                    FLUSH(p6 >> 16, v6) FLUSH(p7 >> 16, v7)
                    e += 8;
                }
                if (e + 3 < cnt) {                        // tail tier 4
                    EDGE(0) EDGE(1) EDGE(2) EDGE(3)
                    FLUSH(p0 >> 16, v0) FLUSH(p1 >> 16, v1)
                    FLUSH(p2 >> 16, v2) FLUSH(p3 >> 16, v3)
                    e += 4;
                }
                if (e + 1 < cnt) {                        // tail tier 2
                    EDGE(0) EDGE(1)
                    FLUSH(p0 >> 16, v0) FLUSH(p1 >> 16, v1)
                    e += 2;
                }
                if (e < cnt) {                            // tail tier 1
                    EDGE(0)
                    FLUSH(p0 >> 16, v0)
                }
                i += 64;
                pv = pv2;
            }
            scat[dl][cur * 64 + c] = f2bf(acc);
        }
        __syncthreads();

        // MFMA [16,512]@[512,64] on waves 0..3; C/D col=lane&15, row=quad*4+r (m89/m91)
        if (wave < 4) {
            const int m = lane & 15;
            const int quad = lane >> 4;
            const int n0 = wave * 16;
            f32x4 acc4 = {0.f, 0.f, 0.f, 0.f};
            const unsigned short* wrow = WT + (size_t)(n0 + m) * 512;
            #pragma unroll
            for (int kc = 0; kc < 16; ++kc) {
                short8 af = *(const short8*)&scat[m][kc * 32 + quad * 8];
                short8 bf = *(const short8*)(wrow + kc * 32 + quad * 8);
                acc4 = __builtin_amdgcn_mfma_f32_16x16x32_bf16(af, bf, acc4, 0, 0, 0);
            }
            const int col = n0 + m;
            const float bcol = bias[col];
            #pragma unroll
            for (int r = 0; r < 4; ++r) {
                int node = dbase + quad * 4 + r;
                Hb[(size_t)node * 64 + col] = f2bf(fmaxf(acc4[r] + bcol, 0.f));
            }
        }
        __syncthreads();   // MFMA readers done before next tile's zeroing
    }
}

// -------- adversary MLP via MFMA + h1 residual (R13-proven) --------
__global__ __launch_bounds__(256) void adv_mfma(const unsigned short* __restrict__ h2b,
                                                const unsigned short* __restrict__ Wa1T, // [128][64] bf16
                                                const float* __restrict__ ba1,           // [128]
                                                const unsigned short* __restrict__ Wa2T, // [64][128] bf16
                                                const float* __restrict__ ba2,           // [64]
                                                const unsigned short* __restrict__ h1b,
                                                float* __restrict__ out) {
    __shared__ unsigned short sH[64][72];
    __shared__ unsigned short sT[64][136];
    const int nbase = blockIdx.x * 64;
    const int tid = threadIdx.x;
    const int lane = tid & 63;
    const int wave = tid >> 6;
    const int m = lane & 15;
    const int quad = lane >> 4;
    const int r0 = wave * 16;

    #pragma unroll
    for (int i = 0; i < 2; ++i) {
        int idx = tid * 2 + i;
        int row = idx >> 3;
        int c8  = (idx & 7) * 8;
        int node = nbase + row;
        short8 u = {};
        if (node < N_NODES)
            u = *(const short8*)(h2b + (size_t)node * C_FEAT + c8);
        *(short8*)&sH[row][c8] = u;
    }
    __syncthreads();

    {   // GEMM1: [16,64] @ [64,128] per wave -> sT rows r0..r0+15
        f32x4 acc1[8];
        #pragma unroll
        for (int ct = 0; ct < 8; ++ct) acc1[ct] = (f32x4){0.f, 0.f, 0.f, 0.f};
        #pragma unroll
        for (int kc = 0; kc < 2; ++kc) {
            short8 af = *(const short8*)&sH[r0 + m][kc * 32 + quad * 8];
            #pragma unroll
            for (int ct = 0; ct < 8; ++ct) {
                short8 bf = *(const short8*)(Wa1T + (size_t)(ct * 16 + m) * 64 + kc * 32 + quad * 8);
                acc1[ct] = __builtin_amdgcn_mfma_f32_16x16x32_bf16(af, bf, acc1[ct], 0, 0, 0);
            }
        }
        #pragma unroll
        for (int ct = 0; ct < 8; ++ct) {
            const int col = ct * 16 + m;
            const float b1 = ba1[col];
            #pragma unroll
            for (int r = 0; r < 4; ++r)
                sT[r0 + quad * 4 + r][col] = f2bf(fmaxf(acc1[ct][r] + b1, 0.f));
        }
    }
    __syncthreads();

    {   // GEMM2: [16,128] @ [128,64] per wave -> out rows r0..r0+15 (+ba2 +h1)
        f32x4 acc2[4];
        #pragma unroll
        for (int ct = 0; ct < 4; ++ct) acc2[ct] = (f32x4){0.f, 0.f, 0.f, 0.f};
        #pragma unroll
        for (int kc = 0; kc < 4; ++kc) {
            short8 af = *(const short8*)&sT[r0 + m][kc * 32 + quad * 8];
            #pragma unroll
            for (int ct = 0; ct < 4; ++ct) {
                short8 bf = *(const short8*)(Wa2T + (size_t)(ct * 16 + m) * 128 + kc * 32 + quad * 8);
                acc2[ct] = __builtin_amdgcn_mfma_f32_16x16x32_bf16(af, bf, acc2[ct], 0, 0, 0);
            }
        }
        #pragma unroll
        for (int ct = 0; ct < 4; ++ct) {
            const int col = ct * 16 + m;
            const float b2 = ba2[col];
            #pragma unroll
            for (int r = 0; r < 4; ++r) {
                int node = nbase + r0 + quad * 4 + r;
                if (node < N_NODES) {
                    float val = acc2[ct][r] + b2 + bf2f(h1b[(size_t)node * 64 + col]);
                    out[(size_t)node * 64 + col] = val;
                }
            }
        }
    }
}

extern "C" void kernel_launch(void* const* d_in, const int* in_sizes, int n_in,
                              void* d_out, int out_size, void* d_ws, size_t ws_size,
                              hipStream_t stream) {
    const float* x   = (const float*)d_in[0];
    const int*   ei  = (const int*)d_in[1];
    const int*   tix = (const int*)d_in[2];
    const float* Wt1 = (const float*)d_in[3];
    const float* bt1 = (const float*)d_in[4];
    const float* Wt2 = (const float*)d_in[5];
    const float* bt2 = (const float*)d_in[6];
    const float* Wa1 = (const float*)d_in[7];
    const float* ba1 = (const float*)d_in[8];
    const float* Wa2 = (const float*)d_in[9];
    const float* ba2 = (const float*)d_in[10];
    float* out = (float*)d_out;

    const int* src = ei;
    const int* dst = ei + E_EDGES;

    // workspace (~23 MB)
    unsigned short* xb   = (unsigned short*)d_ws;          // [N,64] bf16
    unsigned short* h1b  = xb + (size_t)N_NODES * 64;      // [N,64] bf16
    unsigned short* h2b  = h1b + (size_t)N_NODES * 64;     // [N,64] bf16
    unsigned short* WT1  = h2b + (size_t)N_NODES * 64;     // [64,512] bf16
    unsigned short* WT2  = WT1 + 64 * 512;
    unsigned short* Wa1T = WT2 + 64 * 512;                 // [128,64] bf16
    unsigned short* Wa2T = Wa1T + 8192;                    // [64,128] bf16
    int* cnt      = (int*)(Wa2T + 8192);                   // KEYS
    int* bsum     = cnt + KEYS;                            // 512
    int* chunkoff = bsum + 512;                            // 512
    int* done     = chunkoff + 512;                        // 64 (1 used)
    int* bcur     = done + 64;                             // 64 (8 used: bucket cursors)
    int* elist    = bcur + 64;                             // E packed (src | t<<16)
    int2* staging = (int2*)(elist + E_EDGES);              // 8 x BUCKSZ records

    const int aBlk = (N_NODES + 63) / 64;                 // 782

    hipMemsetAsync(cnt, 0, (KEYS + 512 + 512 + 64 + 64) * sizeof(int), stream);
    prep_hist<<<PBLK_X + PBLK_W + PBLK_A + PBLK_P, 256, 0, stream>>>(
        x, Wt1, Wt2, Wa1, Wa2, src, dst, tix, xb, WT1, WT2, Wa1T, Wa2T,
        cnt, bcur, staging);
    scan_all<<<NBLK1, 256, 0, stream>>>(cnt, bsum, chunkoff, done);
    scatter_edges<<<1024, 256, 0, stream>>>(staging, bcur, cnt, chunkoff, elist);

    fused_conv<<<CONV_GRID, 512, 0, stream>>>(xb,  WT1, bt1, cnt, chunkoff, elist, h1b);
    fused_conv<<<CONV_GRID, 512, 0, stream>>>(h1b, WT2, bt2, cnt, chunkoff, elist, h2b);

    adv_mfma<<<aBlk, 256, 0, stream>>>(h2b, Wa1T, ba1, Wa2T, ba2, h1b, out);
}

// Round 8
// 281.820 us; speedup vs baseline: 6.4262x; 1.0536x over previous
//
#include <hip/hip_runtime.h>

#define N_NODES 50000
#define C_FEAT  64
#define E_EDGES 800000
#define KEYS    400000          // dst*8 + t
#define NBLK1   391             // ceil(KEYS/1024)
#define DPB     16              // dsts per conv tile -> 16 MFMA rows
#define NTILES  (N_NODES / DPB) // 3125
#define PBLK_X  1563            // x->bf16 cvt blocks (8 elems/thread, last partial)
#define PBLK_W  128             // Wt transpose blocks
#define PBLK_A  64              // Wa1T/Wa2T transpose blocks (2 x 8192)
#define PBLK_H  391             // hist blocks: single pass, 2048 edges/block
#define DPART   6250            // dsts per XCD partition (scatter)
#define CONV_GRID 1024          // persistent: 4 blocks/CU x 256 CU

typedef __attribute__((ext_vector_type(8))) short short8;
typedef __attribute__((ext_vector_type(4))) float f32x4;

__device__ __forceinline__ float bf2f(unsigned short u) {
    union { unsigned int i; float f; } v; v.i = ((unsigned int)u) << 16; return v.f;
}
__device__ __forceinline__ unsigned short f2bf(float f) {
    union { float f; unsigned int i; } v; v.f = f;
    unsigned int r = v.i + 0x7fff + ((v.i >> 16) & 1);   // RNE
    return (unsigned short)(r >> 16);
}

// -------- prep (x->bf16, Wt->WT bf16, Wa->WaT bf16) + single-pass hist --------
__global__ __launch_bounds__(256) void prep_hist(const float* __restrict__ x,
                                                 const float* __restrict__ W1,
                                                 const float* __restrict__ W2,
                                                 const float* __restrict__ Wa1,
                                                 const float* __restrict__ Wa2,
                                                 const int* __restrict__ dst,
                                                 const int* __restrict__ tix,
                                                 unsigned short* __restrict__ xb,
                                                 unsigned short* __restrict__ WT1,
                                                 unsigned short* __restrict__ WT2,
                                                 unsigned short* __restrict__ Wa1T,
                                                 unsigned short* __restrict__ Wa2T,
                                                 int* __restrict__ cnt) {
    const int b = blockIdx.x;
    if (b < PBLK_X) {
        int base = (b * 256 + threadIdx.x) * 8;
        if (base < N_NODES * 64) {
            float4 a = *(const float4*)(x + base);
            float4 c = *(const float4*)(x + base + 4);
            short8 o;
            o[0] = (short)f2bf(a.x); o[1] = (short)f2bf(a.y);
            o[2] = (short)f2bf(a.z); o[3] = (short)f2bf(a.w);
            o[4] = (short)f2bf(c.x); o[5] = (short)f2bf(c.y);
            o[6] = (short)f2bf(c.z); o[7] = (short)f2bf(c.w);
            *(short8*)(xb + base) = o;
        }
    } else if (b < PBLK_X + PBLK_W) {
        int i = (b - PBLK_X) * 256 + threadIdx.x;      // 32768
        int n = i >> 9, k = i & 511;
        WT1[i] = f2bf(W1[k * 64 + n]);
        WT2[i] = f2bf(W2[k * 64 + n]);
    } else if (b < PBLK_X + PBLK_W + PBLK_A) {
        int i = (b - PBLK_X - PBLK_W) * 256 + threadIdx.x;   // 0..16383
        if (i < 8192) {                                // Wa1T[128][64] <- Wa1[64][128]
            int n = i >> 6, k = i & 63;
            Wa1T[i] = f2bf(Wa1[k * 128 + n]);
        } else {                                       // Wa2T[64][128] <- Wa2[128][64]
            int ii = i - 8192;
            int n = ii >> 7, k = ii & 127;
            Wa2T[ii] = f2bf(Wa2[k * 64 + n]);
        }
    } else {
        // single-pass hist: every edge visited once; atomics fire-and-forget
        int bb = b - PBLK_X - PBLK_W - PBLK_A;         // 0..390
        const int e0 = bb * 2048 + threadIdx.x * 8;
        if (e0 < E_EDGES) {                            // E%8==0 -> window fully in-bounds
            int4 d0 = *(const int4*)(dst + e0);
            int4 d1 = *(const int4*)(dst + e0 + 4);
            int4 t0 = *(const int4*)(tix + e0);
            int4 t1 = *(const int4*)(tix + e0 + 4);
            int dd[8] = {d0.x, d0.y, d0.z, d0.w, d1.x, d1.y, d1.z, d1.w};
            int tt[8] = {t0.x, t0.y, t0.z, t0.w, t1.x, t1.y, t1.z, t1.w};
            #pragma unroll
            for (int k = 0; k < 8; ++k)
                atomicAdd(&cnt[dd[k] * 8 + tt[k]], 1);
        }
    }
}

// -------- scan_all: per-chunk local scan; LAST block scans chunk totals --------
__global__ __launch_bounds__(256) void scan_all(int* __restrict__ cnt,
                                                int* __restrict__ bsum,
                                                int* __restrict__ chunkoff,
                                                int* __restrict__ done) {
    __shared__ int wsum[4];
    __shared__ int ticket;
    const int tid = threadIdx.x;
    const int lane = tid & 63;
    const int wave = tid >> 6;
    const int i4 = blockIdx.x * 256 + tid;
    int4 v = make_int4(0, 0, 0, 0);
    const bool ok = (i4 * 4 < KEYS);
    if (ok) v = ((const int4*)cnt)[i4];
    int s = v.x + v.y + v.z + v.w;
    int sc = s;
    #pragma unroll
    for (int d = 1; d < 64; d <<= 1) {
        int o = __shfl_up(sc, d, 64);
        if (lane >= d) sc += o;
    }
    if (lane == 63) wsum[wave] = sc;
    __syncthreads();
    int wbase = 0;
    #pragma unroll
    for (int w = 0; w < 4; ++w) wbase += (w < wave) ? wsum[w] : 0;
    int base = wbase + sc - s;
    int4 o;
    o.x = base;
    o.y = base + v.x;
    o.z = o.y + v.y;
    o.w = o.z + v.z;
    if (ok) ((int4*)cnt)[i4] = o;
    if (tid == 255) {
        bsum[blockIdx.x] = wbase + sc;
        __threadfence();
        ticket = atomicAdd(done, 1);
    }
    __syncthreads();
    if (ticket == NBLK1 - 1 && wave == 0) {
        int carry = 0;
        #pragma unroll
        for (int g = 0; g < (NBLK1 + 63) / 64; ++g) {
            int j = g * 64 + lane;
            int val = (j < NBLK1) ? atomicAdd(&bsum[j], 0) : 0;
            int scn = val;
            #pragma unroll
            for (int d = 1; d < 64; d <<= 1) {
                int oo = __shfl_up(scn, d, 64);
                if (lane >= d) scn += oo;
            }
            if (j < NBLK1) chunkoff[j] = carry + scn - val;
            carry += __shfl(scn, 63, 64);
        }
    }
}

// -------- XCD-partitioned scatter (8-pass, proven): elist word now carries dlocal --------
__global__ __launch_bounds__(256) void scatter_edges(const int* __restrict__ src,
                                                     const int* __restrict__ dst,
                                                     const int* __restrict__ tix,
                                                     int* __restrict__ cursor,
                                                     const int* __restrict__ chunkoff,
                                                     int* __restrict__ elist) {
    const int g = blockIdx.x & 7;                    // partition (XCD-affine)
    const int lo = g * DPART;
    const int e0 = (blockIdx.x >> 3) * 2048 + threadIdx.x * 8;
    if (e0 < E_EDGES) {                              // E%8==0 -> window fully in-bounds
        int4 d0 = *(const int4*)(dst + e0);
        int4 d1 = *(const int4*)(dst + e0 + 4);
        int4 t0 = *(const int4*)(tix + e0);
        int4 t1 = *(const int4*)(tix + e0 + 4);
        int4 s0 = *(const int4*)(src + e0);
        int4 s1 = *(const int4*)(src + e0 + 4);
        int dd[8] = {d0.x, d0.y, d0.z, d0.w, d1.x, d1.y, d1.z, d1.w};
        int tt[8] = {t0.x, t0.y, t0.z, t0.w, t1.x, t1.y, t1.z, t1.w};
        int ss[8] = {s0.x, s0.y, s0.z, s0.w, s1.x, s1.y, s1.z, s1.w};
        #pragma unroll
        for (int k = 0; k < 8; ++k) {
            if ((unsigned)(dd[k] - lo) < (unsigned)DPART) {
                int key = dd[k] * 8 + tt[k];
                int pos = chunkoff[key >> 10] + atomicAdd(&cursor[key], 1);
                elist[pos] = ss[k] | (tt[k] << 16) | ((dd[k] & 15) << 19);
            }
        }
    }
}

// -------- fused conv: persistent, 8 waves x 1 contiguous dst-pair stream, 32-deep --------
// FLUSH keys on combined (dl,t) field (p>>16, 7 bits). cur initialized from the
// stream's first edge so no spurious cross-wave zero-write.
#define FLUSH(P, V)                                                                   \
    { int _k = (P) >> 16;                                                             \
      if (_k != cur) { scat[cur >> 3][(cur & 7) * 64 + c] = f2bf(acc);                \
                       acc = 0.f; cur = _k; }                                         \
      acc += (V); }

#define EDGE(K)                                                                       \
    int p##K = __builtin_amdgcn_readlane(pv, e + K);                                  \
    float v##K = bf2f(Xb[(size_t)(p##K & 0xffff) * 64 + c]);

template <bool ADV>
__global__ __launch_bounds__(512, 8) void fused_conv(const unsigned short* __restrict__ Xb,
                                                     const unsigned short* __restrict__ WT,
                                                     const float* __restrict__ bias,
                                                     const int* __restrict__ segend,   // local ends
                                                     const int* __restrict__ chunkoff,
                                                     const int* __restrict__ elist,
                                                     unsigned short* __restrict__ Hb,
                                                     const unsigned short* __restrict__ Wa1T,
                                                     const float* __restrict__ ba1,
                                                     const unsigned short* __restrict__ Wa2T,
                                                     const float* __restrict__ ba2,
                                                     const unsigned short* __restrict__ h1r,
                                                     float* __restrict__ outF) {
    __shared__ __attribute__((aligned(16))) unsigned short scat[DPB][520];
    // adv-phase aliases over the scat pool (used only after a barrier)
    unsigned short (*sH)[72]  = (unsigned short(*)[72])&scat[0][0];          // 2304 B
    unsigned short (*sT)[136] = (unsigned short(*)[136])((char*)scat + 4096); // 4352 B
    const int lane = threadIdx.x & 63;
    const int wave = threadIdx.x >> 6;               // 0..7
    const int c = lane;

    for (int tile = blockIdx.x; tile < NTILES; tile += CONV_GRID) {
        const int dbase = tile * DPB;

        {   // zero own 2 rows
            short8 z = {};
            *(short8*)&scat[wave * 2 + 0][lane * 8] = z;
            *(short8*)&scat[wave * 2 + 1][lane * 8] = z;
        }

        // contiguous stream for dst pair {dbase+2w, dbase+2w+1}
        const int dpair = dbase + wave * 2;
        const int k0 = dpair * 8;
        const int sbeg = (dpair == 0) ? 0 : chunkoff[(k0 - 1) >> 10] + segend[k0 - 1];
        const int send = chunkoff[(k0 + 15) >> 10] + segend[k0 + 15];
        int pv = (lane < send - sbeg) ? elist[sbeg + lane] : 0;

        {
            int i = sbeg;
            int cur = 0;
            float acc = 0.f;
            if (i < send) cur = __builtin_amdgcn_readlane(pv, 0) >> 16;
            while (i < send) {
                int cnt = send - i; cnt = (cnt > 64) ? 64 : cnt;
                int pvn = 0;
                if (i + 64 < send) pvn = (lane < send - i - 64) ? elist[i + 64 + lane] : 0;
                int e = 0;
                for (; e + 31 < cnt; e += 32) {          // 32 gathers in flight
                    EDGE(0)  EDGE(1)  EDGE(2)  EDGE(3)
                    EDGE(4)  EDGE(5)  EDGE(6)  EDGE(7)
                    EDGE(8)  EDGE(9)  EDGE(10) EDGE(11)
                    EDGE(12) EDGE(13) EDGE(14) EDGE(15)
                    EDGE(16) EDGE(17) EDGE(18) EDGE(19)
                    EDGE(20) EDGE(21) EDGE(22) EDGE(23)
                    EDGE(24) EDGE(25) EDGE(26) EDGE(27)
                    EDGE(28) EDGE(29) EDGE(30) EDGE(31)
                    FLUSH(p0, v0)   FLUSH(p1, v1)   FLUSH(p2, v2)   FLUSH(p3, v3)
                    FLUSH(p4, v4)   FLUSH(p5, v5)   FLUSH(p6, v6)   FLUSH(p7, v7)
                    FLUSH(p8, v8)   FLUSH(p9, v9)   FLUSH(p10, v10) FLUSH(p11, v11)
                    FLUSH(p12, v12) FLUSH(p13, v13) FLUSH(p14, v14) FLUSH(p15, v15)
                    FLUSH(p16, v16) FLUSH(p17, v17) FLUSH(p18, v18) FLUSH(p19, v19)
                    FLUSH(p20, v20) FLUSH(p21, v21) FLUSH(p22, v22) FLUSH(p23, v23)
                    FLUSH(p24, v24) FLUSH(p25, v25) FLUSH(p26, v26) FLUSH(p27, v27)
                    FLUSH(p28, v28) FLUSH(p29, v29) FLUSH(p30, v30) FLUSH(p31, v31)
                }
                if (e + 15 < cnt) {                      // tail tier 16
                    EDGE(0)  EDGE(1)  EDGE(2)  EDGE(3)
                    EDGE(4)  EDGE(5)  EDGE(6)  EDGE(7)
                    EDGE(8)  EDGE(9)  EDGE(10) EDGE(11)
                    EDGE(12) EDGE(13) EDGE(14) EDGE(15)
                    FLUSH(p0, v0)   FLUSH(p1, v1)   FLUSH(p2, v2)   FLUSH(p3, v3)
                    FLUSH(p4, v4)   FLUSH(p5, v5)   FLUSH(p6, v6)   FLUSH(p7, v7)
                    FLUSH(p8, v8)   FLUSH(p9, v9)   FLUSH(p10, v10) FLUSH(p11, v11)
                    FLUSH(p12, v12) FLUSH(p13, v13) FLUSH(p14, v14) FLUSH(p15, v15)
                    e += 16;
                }
                if (e + 7 < cnt) {                       // tail tier 8
                    EDGE(0) EDGE(1) EDGE(2) EDGE(3) EDGE(4) EDGE(5) EDGE(6) EDGE(7)
                    FLUSH(p0, v0) FLUSH(p1, v1) FLUSH(p2, v2) FLUSH(p3, v3)
                    FLUSH(p4, v4) FLUSH(p5, v5) FLUSH(p6, v6) FLUSH(p7, v7)
                    e += 8;
                }
                if (e + 3 < cnt) {                       // tail tier 4
                    EDGE(0) EDGE(1) EDGE(2) EDGE(3)
                    FLUSH(p0, v0) FLUSH(p1, v1) FLUSH(p2, v2) FLUSH(p3, v3)
                    e += 4;
                }
                if (e + 1 < cnt) {                       // tail tier 2
                    EDGE(0) EDGE(1)
                    FLUSH(p0, v0) FLUSH(p1, v1)
                    e += 2;
                }
                if (e < cnt) {                           // tail tier 1
                    EDGE(0)
                    FLUSH(p0, v0)
                }
                i += 64;
                pv = pvn;
            }
            if (sbeg < send)
                scat[cur >> 3][(cur & 7) * 64 + c] = f2bf(acc);
        }
        __syncthreads();

        // MFMA [16,512]@[512,64] on waves 0..3; C/D col=lane&15, row=quad*4+r (m89/m91)
        const int m = lane & 15;
        const int quad = lane >> 4;
        f32x4 acc4 = {0.f, 0.f, 0.f, 0.f};
        if (wave < 4) {
            const int n0 = wave * 16;
            const unsigned short* wrow = WT + (size_t)(n0 + m) * 512;
            #pragma unroll
            for (int kc = 0; kc < 16; ++kc) {
                short8 af = *(const short8*)&scat[m][kc * 32 + quad * 8];
                short8 bf = *(const short8*)(wrow + kc * 32 + quad * 8);
                acc4 = __builtin_amdgcn_mfma_f32_16x16x32_bf16(af, bf, acc4, 0, 0, 0);
            }
        }

        if (!ADV) {
            if (wave < 4) {
                const int col = wave * 16 + m;
                const float bcol = bias[col];
                #pragma unroll
                for (int r = 0; r < 4; ++r) {
                    int node = dbase + quad * 4 + r;
                    Hb[(size_t)node * 64 + col] = f2bf(fmaxf(acc4[r] + bcol, 0.f));
                }
            }
        } else {
            // ---- fused adversary MLP on this tile's 16 nodes ----
            __syncthreads();                     // all scat MFMA reads complete
            if (wave < 4) {                      // h2 (relu'd, bf16) -> sH
                const int col = wave * 16 + m;
                const float bcol = bias[col];
                #pragma unroll
                for (int r = 0; r < 4; ++r)
                    sH[quad * 4 + r][col] = f2bf(fmaxf(acc4[r] + bcol, 0.f));
            }
            __syncthreads();
            {   // GEMM1: [16,64]@[64,128]; 8 waves, one 16-col tile each
                f32x4 a1 = {0.f, 0.f, 0.f, 0.f};
                const int col = wave * 16 + m;
                #pragma unroll
                for (int kc = 0; kc < 2; ++kc) {
                    short8 af = *(const short8*)&sH[m][kc * 32 + quad * 8];
                    short8 bf = *(const short8*)(Wa1T + (size_t)col * 64 + kc * 32 + quad * 8);
                    a1 = __builtin_amdgcn_mfma_f32_16x16x32_bf16(af, bf, a1, 0, 0, 0);
                }
                const float b1 = ba1[col];
                #pragma unroll
                for (int r = 0; r < 4; ++r)
                    sT[quad * 4 + r][col] = f2bf(fmaxf(a1[r] + b1, 0.f));
            }
            __syncthreads();
            if (wave < 4) {                      // GEMM2: [16,128]@[128,64] + ba2 + h1
                f32x4 a2 = {0.f, 0.f, 0.f, 0.f};
                const int col = wave * 16 + m;
                #pragma unroll
                for (int kc = 0; kc < 4; ++kc) {
                    short8 af = *(const short8*)&sT[m][kc * 32 + quad * 8];
                    short8 bf = *(const short8*)(Wa2T + (size_t)col * 128 + kc * 32 + quad * 8);
                    a2 = __builtin_amdgcn_mfma_f32_16x16x32_bf16(af, bf, a2, 0, 0, 0);
                }
                const float b2 = ba2[col];
                #pragma unroll
                for (int r = 0; r < 4; ++r) {
                    int node = dbase + quad * 4 + r;
                    outF[(size_t)node * 64 + col] =
                        a2[r] + b2 + bf2f(h1r[(size_t)node * 64 + col]);
                }
            }
        }
        __syncthreads();   // all LDS readers done before next tile's zeroing
    }
}

extern "C" void kernel_launch(void* const* d_in, const int* in_sizes, int n_in,
                              void* d_out, int out_size, void* d_ws, size_t ws_size,
                              hipStream_t stream) {
    const float* x   = (const float*)d_in[0];
    const int*   ei  = (const int*)d_in[1];
    const int*   tix = (const int*)d_in[2];
    const float* Wt1 = (const float*)d_in[3];
    const float* bt1 = (const float*)d_in[4];
    const float* Wt2 = (const float*)d_in[5];
    const float* bt2 = (const float*)d_in[6];
    const float* Wa1 = (const float*)d_in[7];
    const float* ba1 = (const float*)d_in[8];
    const float* Wa2 = (const float*)d_in[9];
    const float* ba2 = (const float*)d_in[10];
    float* out = (float*)d_out;

    const int* src = ei;
    const int* dst = ei + E_EDGES;

    // workspace (~25 MB)
    unsigned short* xb   = (unsigned short*)d_ws;          // [N,64] bf16
    unsigned short* h1b  = xb + (size_t)N_NODES * 64;      // [N,64] bf16
    unsigned short* h2b  = h1b + (size_t)N_NODES * 64;     // [N,64] bf16 (unused now)
    unsigned short* WT1  = h2b + (size_t)N_NODES * 64;     // [64,512] bf16
    unsigned short* WT2  = WT1 + 64 * 512;
    unsigned short* Wa1T = WT2 + 64 * 512;                 // [128,64] bf16
    unsigned short* Wa2T = Wa1T + 8192;                    // [64,128] bf16
    int* cnt      = (int*)(Wa2T + 8192);                   // KEYS
    int* bsum     = cnt + KEYS;                            // 512
    int* chunkoff = bsum + 512;                            // 512
    int* done     = chunkoff + 512;                        // 64 (1 used)
    int* elist    = done + 64;                             // E packed (src | t<<16 | dl<<19)

    hipMemsetAsync(cnt, 0, (KEYS + 512 + 512 + 64) * sizeof(int), stream);
    prep_hist<<<PBLK_X + PBLK_W + PBLK_A + PBLK_H, 256, 0, stream>>>(
        x, Wt1, Wt2, Wa1, Wa2, dst, tix, xb, WT1, WT2, Wa1T, Wa2T, cnt);
    scan_all<<<NBLK1, 256, 0, stream>>>(cnt, bsum, chunkoff, done);
    scatter_edges<<<8 * 391, 256, 0, stream>>>(src, dst, tix, cnt, chunkoff, elist);

    fused_conv<false><<<CONV_GRID, 512, 0, stream>>>(
        xb, WT1, bt1, cnt, chunkoff, elist, h1b,
        nullptr, nullptr, nullptr, nullptr, nullptr, nullptr);
    fused_conv<true><<<CONV_GRID, 512, 0, stream>>>(
        h1b, WT2, bt2, cnt, chunkoff, elist, nullptr,
        Wa1T, ba1, Wa2T, ba2, h1b, out);
}

// Round 9
// 274.619 us; speedup vs baseline: 6.5947x; 1.0262x over previous
//
#include <hip/hip_runtime.h>

#define N_NODES 50000
#define C_FEAT  64
#define E_EDGES 800000
#define KEYS    400000          // dst*8 + t
#define NBLK1   391             // ceil(KEYS/1024)
#define DPB     16              // dsts per conv tile -> 16 MFMA rows
#define NTILES  (N_NODES / DPB) // 3125
#define PBLK_X  1563            // x->bf16 cvt blocks (8 elems/thread, last partial)
#define PBLK_W  128             // Wt transpose blocks
#define PBLK_A  64              // Wa1T/Wa2T transpose blocks (2 x 8192)
#define PBLK_H  391             // hist blocks: single pass, 2048 edges/block
#define DPART   6250            // dsts per XCD partition (scatter)
#define CONV_GRID 1024          // persistent: 4 blocks/CU x 256 CU

typedef __attribute__((ext_vector_type(8))) short short8;
typedef __attribute__((ext_vector_type(4))) float f32x4;

__device__ __forceinline__ float bf2f(unsigned short u) {
    union { unsigned int i; float f; } v; v.i = ((unsigned int)u) << 16; return v.f;
}
__device__ __forceinline__ unsigned short f2bf(float f) {
    union { float f; unsigned int i; } v; v.f = f;
    unsigned int r = v.i + 0x7fff + ((v.i >> 16) & 1);   // RNE
    return (unsigned short)(r >> 16);
}

// -------- prep (x->bf16, Wt->WT bf16, Wa->WaT bf16) + single-pass hist --------
__global__ __launch_bounds__(256) void prep_hist(const float* __restrict__ x,
                                                 const float* __restrict__ W1,
                                                 const float* __restrict__ W2,
                                                 const float* __restrict__ Wa1,
                                                 const float* __restrict__ Wa2,
                                                 const int* __restrict__ dst,
                                                 const int* __restrict__ tix,
                                                 unsigned short* __restrict__ xb,
                                                 unsigned short* __restrict__ WT1,
                                                 unsigned short* __restrict__ WT2,
                                                 unsigned short* __restrict__ Wa1T,
                                                 unsigned short* __restrict__ Wa2T,
                                                 int* __restrict__ cnt) {
    const int b = blockIdx.x;
    if (b < PBLK_X) {
        int base = (b * 256 + threadIdx.x) * 8;
        if (base < N_NODES * 64) {
            float4 a = *(const float4*)(x + base);
            float4 c = *(const float4*)(x + base + 4);
            short8 o;
            o[0] = (short)f2bf(a.x); o[1] = (short)f2bf(a.y);
            o[2] = (short)f2bf(a.z); o[3] = (short)f2bf(a.w);
            o[4] = (short)f2bf(c.x); o[5] = (short)f2bf(c.y);
            o[6] = (short)f2bf(c.z); o[7] = (short)f2bf(c.w);
            *(short8*)(xb + base) = o;
        }
    } else if (b < PBLK_X + PBLK_W) {
        int i = (b - PBLK_X) * 256 + threadIdx.x;      // 32768
        int n = i >> 9, k = i & 511;
        WT1[i] = f2bf(W1[k * 64 + n]);
        WT2[i] = f2bf(W2[k * 64 + n]);
    } else if (b < PBLK_X + PBLK_W + PBLK_A) {
        int i = (b - PBLK_X - PBLK_W) * 256 + threadIdx.x;   // 0..16383
        if (i < 8192) {                                // Wa1T[128][64] <- Wa1[64][128]
            int n = i >> 6, k = i & 63;
            Wa1T[i] = f2bf(Wa1[k * 128 + n]);
        } else {                                       // Wa2T[64][128] <- Wa2[128][64]
            int ii = i - 8192;
            int n = ii >> 7, k = ii & 127;
            Wa2T[ii] = f2bf(Wa2[k * 64 + n]);
        }
    } else {
        // single-pass hist: every edge visited once; atomics fire-and-forget
        int bb = b - PBLK_X - PBLK_W - PBLK_A;         // 0..390
        const int e0 = bb * 2048 + threadIdx.x * 8;
        if (e0 < E_EDGES) {                            // E%8==0 -> window fully in-bounds
            int4 d0 = *(const int4*)(dst + e0);
            int4 d1 = *(const int4*)(dst + e0 + 4);
            int4 t0 = *(const int4*)(tix + e0);
            int4 t1 = *(const int4*)(tix + e0 + 4);
            int dd[8] = {d0.x, d0.y, d0.z, d0.w, d1.x, d1.y, d1.z, d1.w};
            int tt[8] = {t0.x, t0.y, t0.z, t0.w, t1.x, t1.y, t1.z, t1.w};
            #pragma unroll
            for (int k = 0; k < 8; ++k)
                atomicAdd(&cnt[dd[k] * 8 + tt[k]], 1);
        }
    }
}

// -------- scan_all: per-chunk local scan; LAST block scans chunk totals --------
__global__ __launch_bounds__(256) void scan_all(int* __restrict__ cnt,
                                                int* __restrict__ bsum,
                                                int* __restrict__ chunkoff,
                                                int* __restrict__ done) {
    __shared__ int wsum[4];
    __shared__ int ticket;
    const int tid = threadIdx.x;
    const int lane = tid & 63;
    const int wave = tid >> 6;
    const int i4 = blockIdx.x * 256 + tid;
    int4 v = make_int4(0, 0, 0, 0);
    const bool ok = (i4 * 4 < KEYS);
    if (ok) v = ((const int4*)cnt)[i4];
    int s = v.x + v.y + v.z + v.w;
    int sc = s;
    #pragma unroll
    for (int d = 1; d < 64; d <<= 1) {
        int o = __shfl_up(sc, d, 64);
        if (lane >= d) sc += o;
    }
    if (lane == 63) wsum[wave] = sc;
    __syncthreads();
    int wbase = 0;
    #pragma unroll
    for (int w = 0; w < 4; ++w) wbase += (w < wave) ? wsum[w] : 0;
    int base = wbase + sc - s;
    int4 o;
    o.x = base;
    o.y = base + v.x;
    o.z = o.y + v.y;
    o.w = o.z + v.z;
    if (ok) ((int4*)cnt)[i4] = o;
    if (tid == 255) {
        bsum[blockIdx.x] = wbase + sc;
        __threadfence();
        ticket = atomicAdd(done, 1);
    }
    __syncthreads();
    if (ticket == NBLK1 - 1 && wave == 0) {
        int carry = 0;
        #pragma unroll
        for (int g = 0; g < (NBLK1 + 63) / 64; ++g) {
            int j = g * 64 + lane;
            int val = (j < NBLK1) ? atomicAdd(&bsum[j], 0) : 0;
            int scn = val;
            #pragma unroll
            for (int d = 1; d < 64; d <<= 1) {
                int oo = __shfl_up(scn, d, 64);
                if (lane >= d) scn += oo;
            }
            if (j < NBLK1) chunkoff[j] = carry + scn - val;
            carry += __shfl(scn, 63, 64);
        }
    }
}

// -------- XCD-partitioned scatter (8-pass, proven): elist word carries dlocal --------
__global__ __launch_bounds__(256) void scatter_edges(const int* __restrict__ src,
                                                     const int* __restrict__ dst,
                                                     const int* __restrict__ tix,
                                                     int* __restrict__ cursor,
                                                     const int* __restrict__ chunkoff,
                                                     int* __restrict__ elist) {
    const int g = blockIdx.x & 7;                    // partition (XCD-affine)
    const int lo = g * DPART;
    const int e0 = (blockIdx.x >> 3) * 2048 + threadIdx.x * 8;
    if (e0 < E_EDGES) {                              // E%8==0 -> window fully in-bounds
        int4 d0 = *(const int4*)(dst + e0);
        int4 d1 = *(const int4*)(dst + e0 + 4);
        int4 t0 = *(const int4*)(tix + e0);
        int4 t1 = *(const int4*)(tix + e0 + 4);
        int4 s0 = *(const int4*)(src + e0);
        int4 s1 = *(const int4*)(src + e0 + 4);
        int dd[8] = {d0.x, d0.y, d0.z, d0.w, d1.x, d1.y, d1.z, d1.w};
        int tt[8] = {t0.x, t0.y, t0.z, t0.w, t1.x, t1.y, t1.z, t1.w};
        int ss[8] = {s0.x, s0.y, s0.z, s0.w, s1.x, s1.y, s1.z, s1.w};
        #pragma unroll
        for (int k = 0; k < 8; ++k) {
            if ((unsigned)(dd[k] - lo) < (unsigned)DPART) {
                int key = dd[k] * 8 + tt[k];
                int pos = chunkoff[key >> 10] + atomicAdd(&cursor[key], 1);
                elist[pos] = ss[k] | (tt[k] << 16) | ((dd[k] & 15) << 19);
            }
        }
    }
}

// -------- fused conv: persistent, 8 waves x 1 merged dst-pair stream, 16-deep, MFMA --------
// FLUSH keys on combined (dl,t) field (p>>16, 7 bits). cur initialized from the
// stream's first edge so no spurious cross-wave zero-write.
// 16-deep max tier: fits the 64-VGPR budget of (512,8); 32-deep spilled (R8:
// WRITE 39MB of scratch, conv 68us).
#define FLUSH(P, V)                                                                   \
    { int _k = (P) >> 16;                                                             \
      if (_k != cur) { scat[cur >> 3][(cur & 7) * 64 + c] = f2bf(acc);                \
                       acc = 0.f; cur = _k; }                                         \
      acc += (V); }

#define EDGE(K)                                                                       \
    int p##K = __builtin_amdgcn_readlane(pv, e + K);                                  \
    float v##K = bf2f(Xb[(size_t)(p##K & 0xffff) * 64 + c]);

template <bool ADV>
__global__ __launch_bounds__(512, 8) void fused_conv(const unsigned short* __restrict__ Xb,
                                                     const unsigned short* __restrict__ WT,
                                                     const float* __restrict__ bias,
                                                     const int* __restrict__ segend,   // local ends
                                                     const int* __restrict__ chunkoff,
                                                     const int* __restrict__ elist,
                                                     unsigned short* __restrict__ Hb,
                                                     const unsigned short* __restrict__ Wa1T,
                                                     const float* __restrict__ ba1,
                                                     const unsigned short* __restrict__ Wa2T,
                                                     const float* __restrict__ ba2,
                                                     const unsigned short* __restrict__ h1r,
                                                     float* __restrict__ outF) {
    __shared__ __attribute__((aligned(16))) unsigned short scat[DPB][520];
    // adv-phase aliases over the scat pool (used only after a barrier)
    unsigned short (*sH)[72]  = (unsigned short(*)[72])&scat[0][0];          // 2304 B
    unsigned short (*sT)[136] = (unsigned short(*)[136])((char*)scat + 4096); // 4352 B
    const int lane = threadIdx.x & 63;
    const int wave = threadIdx.x >> 6;               // 0..7
    const int c = lane;

    for (int tile = blockIdx.x; tile < NTILES; tile += CONV_GRID) {
        const int dbase = tile * DPB;

        {   // zero own 2 rows
            short8 z = {};
            *(short8*)&scat[wave * 2 + 0][lane * 8] = z;
            *(short8*)&scat[wave * 2 + 1][lane * 8] = z;
        }

        // contiguous stream for dst pair {dbase+2w, dbase+2w+1}
        const int dpair = dbase + wave * 2;
        const int k0 = dpair * 8;
        const int sbeg = (dpair == 0) ? 0 : chunkoff[(k0 - 1) >> 10] + segend[k0 - 1];
        const int send = chunkoff[(k0 + 15) >> 10] + segend[k0 + 15];
        int pv = (lane < send - sbeg) ? elist[sbeg + lane] : 0;

        {
            int i = sbeg;
            int cur = 0;
            float acc = 0.f;
            if (i < send) cur = __builtin_amdgcn_readlane(pv, 0) >> 16;
            while (i < send) {
                int cnt = send - i; cnt = (cnt > 64) ? 64 : cnt;
                int pvn = 0;
                if (i + 64 < send) pvn = (lane < send - i - 64) ? elist[i + 64 + lane] : 0;
                int e = 0;
                for (; e + 15 < cnt; e += 16) {          // 16 gathers in flight
                    EDGE(0)  EDGE(1)  EDGE(2)  EDGE(3)
                    EDGE(4)  EDGE(5)  EDGE(6)  EDGE(7)
                    EDGE(8)  EDGE(9)  EDGE(10) EDGE(11)
                    EDGE(12) EDGE(13) EDGE(14) EDGE(15)
                    FLUSH(p0, v0)   FLUSH(p1, v1)   FLUSH(p2, v2)   FLUSH(p3, v3)
                    FLUSH(p4, v4)   FLUSH(p5, v5)   FLUSH(p6, v6)   FLUSH(p7, v7)
                    FLUSH(p8, v8)   FLUSH(p9, v9)   FLUSH(p10, v10) FLUSH(p11, v11)
                    FLUSH(p12, v12) FLUSH(p13, v13) FLUSH(p14, v14) FLUSH(p15, v15)
                }
                if (e + 7 < cnt) {                       // tail tier 8
                    EDGE(0) EDGE(1) EDGE(2) EDGE(3) EDGE(4) EDGE(5) EDGE(6) EDGE(7)
                    FLUSH(p0, v0) FLUSH(p1, v1) FLUSH(p2, v2) FLUSH(p3, v3)
                    FLUSH(p4, v4) FLUSH(p5, v5) FLUSH(p6, v6) FLUSH(p7, v7)
                    e += 8;
                }
                if (e + 3 < cnt) {                       // tail tier 4
                    EDGE(0) EDGE(1) EDGE(2) EDGE(3)
                    FLUSH(p0, v0) FLUSH(p1, v1) FLUSH(p2, v2) FLUSH(p3, v3)
                    e += 4;
                }
                if (e + 1 < cnt) {                       // tail tier 2
                    EDGE(0) EDGE(1)
                    FLUSH(p0, v0) FLUSH(p1, v1)
                    e += 2;
                }
                if (e < cnt) {                           // tail tier 1
                    EDGE(0)
                    FLUSH(p0, v0)
                }
                i += 64;
                pv = pvn;
            }
            if (sbeg < send)
                scat[cur >> 3][(cur & 7) * 64 + c] = f2bf(acc);
        }
        __syncthreads();

        // MFMA [16,512]@[512,64] on waves 0..3; C/D col=lane&15, row=quad*4+r (m89/m91)
        const int m = lane & 15;
        const int quad = lane >> 4;
        f32x4 acc4 = {0.f, 0.f, 0.f, 0.f};
        if (wave < 4) {
            const int n0 = wave * 16;
            const unsigned short* wrow = WT + (size_t)(n0 + m) * 512;
            #pragma unroll
            for (int kc = 0; kc < 16; ++kc) {
                short8 af = *(const short8*)&scat[m][kc * 32 + quad * 8];
                short8 bf = *(const short8*)(wrow + kc * 32 + quad * 8);
                acc4 = __builtin_amdgcn_mfma_f32_16x16x32_bf16(af, bf, acc4, 0, 0, 0);
            }
        }

        if (!ADV) {
            if (wave < 4) {
                const int col = wave * 16 + m;
                const float bcol = bias[col];
                #pragma unroll
                for (int r = 0; r < 4; ++r) {
                    int node = dbase + quad * 4 + r;
                    Hb[(size_t)node * 64 + col] = f2bf(fmaxf(acc4[r] + bcol, 0.f));
                }
            }
        } else {
            // ---- fused adversary MLP on this tile's 16 nodes ----
            __syncthreads();                     // all scat MFMA reads complete
            if (wave < 4) {                      // h2 (relu'd, bf16) -> sH
                const int col = wave * 16 + m;
                const float bcol = bias[col];
                #pragma unroll
                for (int r = 0; r < 4; ++r)
                    sH[quad * 4 + r][col] = f2bf(fmaxf(acc4[r] + bcol, 0.f));
            }
            __syncthreads();
            {   // GEMM1: [16,64]@[64,128]; 8 waves, one 16-col tile each
                f32x4 a1 = {0.f, 0.f, 0.f, 0.f};
                const int col = wave * 16 + m;
                #pragma unroll
                for (int kc = 0; kc < 2; ++kc) {
                    short8 af = *(const short8*)&sH[m][kc * 32 + quad * 8];
                    short8 bf = *(const short8*)(Wa1T + (size_t)col * 64 + kc * 32 + quad * 8);
                    a1 = __builtin_amdgcn_mfma_f32_16x16x32_bf16(af, bf, a1, 0, 0, 0);
                }
                const float b1 = ba1[col];
                #pragma unroll
                for (int r = 0; r < 4; ++r)
                    sT[quad * 4 + r][col] = f2bf(fmaxf(a1[r] + b1, 0.f));
            }
            __syncthreads();
            if (wave < 4) {                      // GEMM2: [16,128]@[128,64] + ba2 + h1
                f32x4 a2 = {0.f, 0.f, 0.f, 0.f};
                const int col = wave * 16 + m;
                #pragma unroll
                for (int kc = 0; kc < 4; ++kc) {
                    short8 af = *(const short8*)&sT[m][kc * 32 + quad * 8];
                    short8 bf = *(const short8*)(Wa2T + (size_t)col * 128 + kc * 32 + quad * 8);
                    a2 = __builtin_amdgcn_mfma_f32_16x16x32_bf16(af, bf, a2, 0, 0, 0);
                }
                const float b2 = ba2[col];
                #pragma unroll
                for (int r = 0; r < 4; ++r) {
                    int node = dbase + quad * 4 + r;
                    outF[(size_t)node * 64 + col] =
                        a2[r] + b2 + bf2f(h1r[(size_t)node * 64 + col]);
                }
            }
        }
        __syncthreads();   // all LDS readers done before next tile's zeroing
    }
}

extern "C" void kernel_launch(void* const* d_in, const int* in_sizes, int n_in,
                              void* d_out, int out_size, void* d_ws, size_t ws_size,
                              hipStream_t stream) {
    const float* x   = (const float*)d_in[0];
    const int*   ei  = (const int*)d_in[1];
    const int*   tix = (const int*)d_in[2];
    const float* Wt1 = (const float*)d_in[3];
    const float* bt1 = (const float*)d_in[4];
    const float* Wt2 = (const float*)d_in[5];
    const float* bt2 = (const float*)d_in[6];
    const float* Wa1 = (const float*)d_in[7];
    const float* ba1 = (const float*)d_in[8];
    const float* Wa2 = (const float*)d_in[9];
    const float* ba2 = (const float*)d_in[10];
    float* out = (float*)d_out;

    const int* src = ei;
    const int* dst = ei + E_EDGES;

    // workspace (~25 MB)
    unsigned short* xb   = (unsigned short*)d_ws;          // [N,64] bf16
    unsigned short* h1b  = xb + (size_t)N_NODES * 64;      // [N,64] bf16
    unsigned short* h2b  = h1b + (size_t)N_NODES * 64;     // [N,64] bf16 (unused now)
    unsigned short* WT1  = h2b + (size_t)N_NODES * 64;     // [64,512] bf16
    unsigned short* WT2  = WT1 + 64 * 512;
    unsigned short* Wa1T = WT2 + 64 * 512;                 // [128,64] bf16
    unsigned short* Wa2T = Wa1T + 8192;                    // [64,128] bf16
    int* cnt      = (int*)(Wa2T + 8192);                   // KEYS
    int* bsum     = cnt + KEYS;                            // 512
    int* chunkoff = bsum + 512;                            // 512
    int* done     = chunkoff + 512;                        // 64 (1 used)
    int* elist    = done + 64;                             // E packed (src | t<<16 | dl<<19)

    hipMemsetAsync(cnt, 0, (KEYS + 512 + 512 + 64) * sizeof(int), stream);
    prep_hist<<<PBLK_X + PBLK_W + PBLK_A + PBLK_H, 256, 0, stream>>>(
        x, Wt1, Wt2, Wa1, Wa2, dst, tix, xb, WT1, WT2, Wa1T, Wa2T, cnt);
    scan_all<<<NBLK1, 256, 0, stream>>>(cnt, bsum, chunkoff, done);
    scatter_edges<<<8 * 391, 256, 0, stream>>>(src, dst, tix, cnt, chunkoff, elist);

    fused_conv<false><<<CONV_GRID, 512, 0, stream>>>(
        xb, WT1, bt1, cnt, chunkoff, elist, h1b,
        nullptr, nullptr, nullptr, nullptr, nullptr, nullptr);
    fused_conv<true><<<CONV_GRID, 512, 0, stream>>>(
        h1b, WT2, bt2, cnt, chunkoff, elist, nullptr,
        Wa1T, ba1, Wa2T, ba2, h1b, out);
}